// Round 15
// baseline (182.817 us; speedup 1.0000x reference)
//
#include <hip/hip_runtime.h>
#include <hip/hip_bf16.h>
#include <math.h>

// Problem constants (fixed shapes from setup_inputs)
#define NB    8
#define CIN   128
#define CO    32
#define CH    64            // 2*Co channels in qk
#define NN    65536         // H*W
#define CPB   512           // columns per gram block
#define GBLK  (NN/CPB)      // 128 gram blocks per batch
#define TCOLS 128           // columns per LDS tile
#define NTILES (CPB/TCOLS)  // 4 tiles per block

typedef __attribute__((ext_vector_type(8))) short bf16x8;
typedef __attribute__((ext_vector_type(16))) float f32x16;

__device__ __forceinline__ short f2bf(float f) {
    union { __hip_bfloat16 h; short s; } u;
    u.h = __float2bfloat16(f);
    return u.s;
}
__device__ __forceinline__ float bf2f(short s) {
    union { __hip_bfloat16 h; short s; } u;
    u.s = s;
    return __bfloat162float(u.h);
}

// ---------------------------------------------------------------------------
// Kernel A v6 (EXACT R9): reg-staged dbuf, swizzled LDS, 32x32x16 bf16 MFMA
// hi/lo split. part[b][blk][q*32+k], partsq[b][blk][ch] (0..31=k, 32..63=q)
// ---------------------------------------------------------------------------
__global__ __launch_bounds__(256) void gram_kernel(const float* __restrict__ qk,
                                                   float* __restrict__ part,
                                                   float* __restrict__ partsq) {
    __shared__ float smem[CH * TCOLS];   // 32 KB; reused for epilogue reduce
    float4* tile4 = (float4*)smem;       // [64][32] float4 view

    const int b = blockIdx.y;
    const int blk = blockIdx.x;
    const int t = threadIdx.x;
    const int w = t >> 6;
    const int l = t & 63;
    const int c = l & 31;
    const int half = l >> 5;

    const float* qkb = qk + (size_t)b * CH * NN;
    const size_t colbase0 = (size_t)blk * CPB;

    const int lrow[8] = {  (t) >> 5, (t + 256) >> 5, (t + 512) >> 5, (t + 768) >> 5,
                           (t + 1024) >> 5, (t + 1280) >> 5, (t + 1536) >> 5, (t + 1792) >> 5 };
    const int lcol4 = t & 31;

    f32x16 acc = {};
    float sq[8] = {0.f, 0.f, 0.f, 0.f, 0.f, 0.f, 0.f, 0.f};

    // ---- preload tile 0 into registers
    float4 st[8];
#pragma unroll
    for (int k = 0; k < 8; ++k)
        st[k] = *(const float4*)(qkb + (size_t)lrow[k] * NN + colbase0 + lcol4 * 4);

#pragma unroll
    for (int tau = 0; tau < NTILES; ++tau) {
        // ---- drain staged regs into swizzled LDS (+ square-sums)
#pragma unroll
        for (int k = 0; k < 8; ++k) {
            float4 v = st[k];
            sq[k] = fmaf(v.x, v.x, sq[k]);
            sq[k] = fmaf(v.y, v.y, sq[k]);
            sq[k] = fmaf(v.z, v.z, sq[k]);
            sq[k] = fmaf(v.w, v.w, sq[k]);
            tile4[lrow[k] * 32 + (lcol4 ^ (lrow[k] & 7))] = v;
        }
        __syncthreads();

        // ---- issue next tile's loads (in flight during compute below)
        if (tau + 1 < NTILES) {
            const size_t colbase = colbase0 + (size_t)(tau + 1) * TCOLS;
#pragma unroll
            for (int k = 0; k < 8; ++k)
                st[k] = *(const float4*)(qkb + (size_t)lrow[k] * NN + colbase + lcol4 * 4);
        }

        // ---- compute: wave w -> sub-slices s = 2w, 2w+1 (16 cols each)
#pragma unroll
        for (int ss = 0; ss < 2; ++ss) {
            const int s = 2 * w + ss;
            const int f0 = s * 4 + half * 2;
            const int qrow = CO + c;
            const int krow = c;
            const int sw = c & 7;
            float4 q0 = tile4[qrow * 32 + (f0 ^ sw)];
            float4 q1 = tile4[qrow * 32 + ((f0 + 1) ^ sw)];
            float4 k0 = tile4[krow * 32 + (f0 ^ sw)];
            float4 k1 = tile4[krow * 32 + ((f0 + 1) ^ sw)];

            float qf[8] = {q0.x, q0.y, q0.z, q0.w, q1.x, q1.y, q1.z, q1.w};
            float kf[8] = {k0.x, k0.y, k0.z, k0.w, k1.x, k1.y, k1.z, k1.w};

            bf16x8 ah, al, bh, bl;
#pragma unroll
            for (int j = 0; j < 8; ++j) {
                short hq = f2bf(qf[j]);
                ah[j] = hq;
                al[j] = f2bf(qf[j] - bf2f(hq));
                short hk = f2bf(kf[j]);
                bh[j] = hk;
                bl[j] = f2bf(kf[j] - bf2f(hk));
            }
            acc = __builtin_amdgcn_mfma_f32_32x32x16_bf16(ah, bh, acc, 0, 0, 0);
            acc = __builtin_amdgcn_mfma_f32_32x32x16_bf16(ah, bl, acc, 0, 0, 0);
            acc = __builtin_amdgcn_mfma_f32_32x32x16_bf16(al, bh, acc, 0, 0, 0);
        }
        __syncthreads();
    }

    // ---- stage per-wave acc: C/D layout col=lane&31 (k), row=(r&3)+8*(r>>2)+4*half (q)
#pragma unroll
    for (int r = 0; r < 16; ++r) {
        int row = (r & 3) + 8 * (r >> 2) + 4 * half;
        smem[w * 1024 + row * 32 + c] = acc[r];
    }
#pragma unroll
    for (int k = 0; k < 8; ++k)
        smem[4096 + ((t >> 5) + 8 * k) * 32 + (t & 31)] = sq[k];
    __syncthreads();

    float* pp = part + ((size_t)b * GBLK + blk) * 1024;
#pragma unroll
    for (int j = 0; j < 4; ++j) {
        int idx = t + j * 256;
        pp[idx] = smem[idx] + smem[1024 + idx] + smem[2048 + idx] + smem[3072 + idx];
    }
    if (t < 64) {
        float s = 0.f;
#pragma unroll
        for (int i = 0; i < 32; ++i) s += smem[4096 + t * 32 + i];
        partsq[((size_t)b * GBLK + blk) * 64 + t] = s;
    }
}

// ---------------------------------------------------------------------------
// Kernel B1: reduce partials over 128 chunks (unchanged from R9)
// ---------------------------------------------------------------------------
__global__ __launch_bounds__(128) void reduce_kernel(const float* __restrict__ part,
                                                     const float* __restrict__ partsq,
                                                     float* __restrict__ Sred) {
    const int b = blockIdx.y;
    const int v = blockIdx.x * 64 + (threadIdx.x >> 1);
    const int h = threadIdx.x & 1;
    float s = 0.f;
    if (v < 1024) {
        const float* p = part + (size_t)b * GBLK * 1024 + v;
        for (int ch = h * (GBLK / 2); ch < (h + 1) * (GBLK / 2); ++ch)
            s += p[(size_t)ch * 1024];
    } else {
        const float* p = partsq + (size_t)b * GBLK * 64 + (v - 1024);
        for (int ch = h * (GBLK / 2); ch < (h + 1) * (GBLK / 2); ++ch)
            s += p[(size_t)ch * 64];
    }
    s += __shfl_xor(s, 1);
    if (h == 0) Sred[b * 1088 + v] = s;
}

// ---------------------------------------------------------------------------
// Kernel B2 (R11 variant): normalize, softmax, W_eff = attn @ w_v emitted as
// bf16 hi/lo SPLIT arrays (ready-to-load MFMA A-fragments); b_eff stays f32.
// ---------------------------------------------------------------------------
__global__ __launch_bounds__(256) void attn_kernel(const float* __restrict__ Sred,
                                                   const float* __restrict__ w_v,
                                                   const float* __restrict__ b_v,
                                                   const float* __restrict__ temp,
                                                   unsigned short* __restrict__ Whi,
                                                   unsigned short* __restrict__ Wlo,
                                                   float* __restrict__ beff) {
    __shared__ float sS[1024];
    __shared__ float snorm[64];
    __shared__ float sA[1024];
    const int t = threadIdx.x;
    const int b = blockIdx.x;

    for (int i = t; i < 1024; i += 256) sS[i] = Sred[b * 1088 + i];
    if (t < 64) snorm[t] = fmaxf(sqrtf(Sred[b * 1088 + 1024 + t]), 1e-12f);
    __syncthreads();

    if (t < 32) {
        const float T = temp[0];
        const float qn = snorm[32 + t];
        float m = -1e30f;
        for (int d = 0; d < 32; ++d)
            m = fmaxf(m, sS[t * 32 + d] / (qn * snorm[d]) * T);
        float sum = 0.f;
        for (int d = 0; d < 32; ++d)
            sum += expf(sS[t * 32 + d] / (qn * snorm[d]) * T - m);
        const float inv = 1.f / sum;
        for (int d = 0; d < 32; ++d)
            sA[t * 32 + d] = expf(sS[t * 32 + d] / (qn * snorm[d]) * T - m) * inv;
    }
    __syncthreads();

    for (int idx = t; idx < CO * CIN; idx += 256) {
        int cc = idx >> 7;
        int ci = idx & 127;
        float s = 0.f;
#pragma unroll
        for (int d = 0; d < 32; ++d) s += sA[cc * 32 + d] * w_v[d * CIN + ci];
        short hi = f2bf(s);
        short lo = f2bf(s - bf2f(hi));
        Whi[(size_t)b * CO * CIN + idx] = (unsigned short)hi;
        Wlo[(size_t)b * CO * CIN + idx] = (unsigned short)lo;
    }
    if (t < 32) {
        float s = 0.f;
#pragma unroll
        for (int d = 0; d < 32; ++d) s += sA[t * 32 + d] * b_v[d];
        beff[b * CO + t] = s;
    }
}

// ---------------------------------------------------------------------------
// Kernel C v7 — gram-structure MFMA out WITH the 4-tile loop + reg-staged
// prefetch (the piece v6 was missing). Block = 512 cols = 4 tiles of 128.
// Per tile: st->LDS(swz) | barrier | issue next tile's 16 float4 | compute
// 24 MFMA from LDS | store tile outputs | barrier. Loads always in flight.
// ---------------------------------------------------------------------------
__global__ __launch_bounds__(256) void out_kernel(const float* __restrict__ x,
                                                  const unsigned short* __restrict__ Whi,
                                                  const unsigned short* __restrict__ Wlo,
                                                  const float* __restrict__ beff,
                                                  float* __restrict__ out) {
    __shared__ float4 tile4[CIN * 32];   // [128 ci][32 col4] swizzled = 64 KB
    const float* lf = (const float*)tile4;

    const int b = blockIdx.y;
    const int t = threadIdx.x;
    const int w = t >> 6;
    const int l = t & 63;
    const int c = l & 31;       // A row (o) / D col offset
    const int half = l >> 5;    // k-half selector

    const float* xb = x + (size_t)b * CIN * NN;
    const int col0 = blockIdx.x * 512;

    // ---- A fragments (W), resident: 16 x b128 loads (32 VGPRs)
    bf16x8 ah[8], al[8];
    {
        const unsigned short* Wh = Whi + (size_t)b * CO * CIN + c * CIN + half * 8;
        const unsigned short* Wl = Wlo + (size_t)b * CO * CIN + c * CIN + half * 8;
#pragma unroll
        for (int s = 0; s < 8; ++s) {
            ah[s] = *(const bf16x8*)(Wh + s * 16);
            al[s] = *(const bf16x8*)(Wl + s * 16);
        }
    }
    float bias[16];
    {
        const float* bb = beff + b * CO;
#pragma unroll
        for (int r = 0; r < 16; ++r)
            bias[r] = bb[(r & 3) + 8 * (r >> 2) + 4 * half];
    }

    const int lci   = t >> 5;         // load row base (ci = lci + 8k... no: flat pattern below)
    const int lcol4 = t & 31;

    // ---- preload tile 0: flat = t + k*256; ci = flat>>5; col4 = flat&31
    float4 st[16];
#pragma unroll
    for (int k = 0; k < 16; ++k) {
        int ci = lci + k * 8;
        st[k] = *(const float4*)(xb + (size_t)ci * NN + col0 + lcol4 * 4);
    }

    const int n = w * 32 + c;        // column within tile owned by this lane

#pragma unroll
    for (int tau = 0; tau < 4; ++tau) {
        // ---- drain staged regs into swizzled LDS
#pragma unroll
        for (int k = 0; k < 16; ++k) {
            int ci = lci + k * 8;
            tile4[ci * 32 + (lcol4 ^ (ci & 7))] = st[k];
        }
        __syncthreads();

        // ---- issue next tile's loads (in flight during compute below)
        if (tau < 3) {
            const int colb = col0 + (tau + 1) * 128;
#pragma unroll
            for (int k = 0; k < 16; ++k) {
                int ci = lci + k * 8;
                st[k] = *(const float4*)(xb + (size_t)ci * NN + colb + lcol4 * 4);
            }
        }

        // ---- compute this tile from LDS
        f32x16 acc = {};
#pragma unroll
        for (int s = 0; s < 8; ++s) {
            float xv[8];
#pragma unroll
            for (int j = 0; j < 8; ++j) {
                int ci = s * 16 + half * 8 + j;
                xv[j] = lf[(ci * 32 + ((n >> 2) ^ (ci & 7))) * 4 + (n & 3)];
            }
            bf16x8 bh, bl;
#pragma unroll
            for (int j = 0; j < 8; ++j) {
                short h = f2bf(xv[j]);
                bh[j] = h;
                bl[j] = f2bf(xv[j] - bf2f(h));
            }
            acc = __builtin_amdgcn_mfma_f32_32x32x16_bf16(ah[s], bh, acc, 0, 0, 0);
            acc = __builtin_amdgcn_mfma_f32_32x32x16_bf16(ah[s], bl, acc, 0, 0, 0);
            acc = __builtin_amdgcn_mfma_f32_32x32x16_bf16(al[s], bh, acc, 0, 0, 0);
        }

        // ---- store this tile's outputs (+bias)
        float* ob = out + (size_t)b * CO * NN + col0 + tau * 128 + n;
#pragma unroll
        for (int r = 0; r < 16; ++r) {
            int o = (r & 3) + 8 * (r >> 2) + 4 * half;
            ob[(size_t)o * NN] = acc[r] + bias[r];
        }
        __syncthreads();   // all LDS reads done before next tile's writes
    }
}

// ---------------------------------------------------------------------------
extern "C" void kernel_launch(void* const* d_in, const int* in_sizes, int n_in,
                              void* d_out, int out_size, void* d_ws, size_t ws_size,
                              hipStream_t stream) {
    const float* x    = (const float*)d_in[0];
    const float* qk   = (const float*)d_in[1];
    const float* w_v  = (const float*)d_in[2];
    const float* b_v  = (const float*)d_in[3];
    const float* temp = (const float*)d_in[4];
    float* out = (float*)d_out;

    float* part   = (float*)d_ws;                         // NB*GBLK*1024 floats (4 MB)
    float* partsq = part + (size_t)NB * GBLK * 1024;      // NB*GBLK*64 floats
    float* Sred   = partsq + (size_t)NB * GBLK * 64;      // NB*1088 floats
    unsigned short* Whi = (unsigned short*)(Sred + (size_t)NB * 1088);  // NB*CO*CIN bf16
    unsigned short* Wlo = Whi + (size_t)NB * CO * CIN;
    float* beff   = (float*)(Wlo + (size_t)NB * CO * CIN);

    gram_kernel<<<dim3(GBLK, NB), 256, 0, stream>>>(qk, part, partsq);
    reduce_kernel<<<dim3(17, NB), 128, 0, stream>>>(part, partsq, Sred);
    attn_kernel<<<dim3(NB), 256, 0, stream>>>(Sred, w_v, b_v, temp, Whi, Wlo, beff);
    out_kernel<<<dim3(NN / 512, NB), 256, 0, stream>>>(x, Whi, Wlo, beff, out);
}

// Round 16
// 119.302 us; speedup vs baseline: 1.5324x; 1.5324x over previous
//
#include <hip/hip_runtime.h>
#include <hip/hip_bf16.h>
#include <math.h>

// Problem constants (fixed shapes from setup_inputs)
#define NB    8
#define CIN   128
#define CO    32
#define CH    64            // 2*Co channels in qk
#define NN    65536         // H*W
#define CPB   512           // columns per gram block
#define GBLK  (NN/CPB)      // 128 gram blocks per batch
#define TCOLS 128           // columns per LDS tile
#define NTILES (CPB/TCOLS)  // 4 tiles per block

typedef __attribute__((ext_vector_type(8))) short bf16x8;
typedef __attribute__((ext_vector_type(16))) float f32x16;

__device__ __forceinline__ short f2bf(float f) {
    union { __hip_bfloat16 h; short s; } u;
    u.h = __float2bfloat16(f);
    return u.s;
}
__device__ __forceinline__ float bf2f(short s) {
    union { __hip_bfloat16 h; short s; } u;
    u.s = s;
    return __bfloat162float(u.h);
}

// ---------------------------------------------------------------------------
// Kernel A v6 (EXACT R9): reg-staged dbuf, swizzled LDS, 32x32x16 bf16 MFMA
// hi/lo split. part[b][blk][q*32+k], partsq[b][blk][ch] (0..31=k, 32..63=q)
// ---------------------------------------------------------------------------
__global__ __launch_bounds__(256) void gram_kernel(const float* __restrict__ qk,
                                                   float* __restrict__ part,
                                                   float* __restrict__ partsq) {
    __shared__ float smem[CH * TCOLS];   // 32 KB; reused for epilogue reduce
    float4* tile4 = (float4*)smem;       // [64][32] float4 view

    const int b = blockIdx.y;
    const int blk = blockIdx.x;
    const int t = threadIdx.x;
    const int w = t >> 6;
    const int l = t & 63;
    const int c = l & 31;
    const int half = l >> 5;

    const float* qkb = qk + (size_t)b * CH * NN;
    const size_t colbase0 = (size_t)blk * CPB;

    const int lrow[8] = {  (t) >> 5, (t + 256) >> 5, (t + 512) >> 5, (t + 768) >> 5,
                           (t + 1024) >> 5, (t + 1280) >> 5, (t + 1536) >> 5, (t + 1792) >> 5 };
    const int lcol4 = t & 31;

    f32x16 acc = {};
    float sq[8] = {0.f, 0.f, 0.f, 0.f, 0.f, 0.f, 0.f, 0.f};

    // ---- preload tile 0 into registers
    float4 st[8];
#pragma unroll
    for (int k = 0; k < 8; ++k)
        st[k] = *(const float4*)(qkb + (size_t)lrow[k] * NN + colbase0 + lcol4 * 4);

#pragma unroll
    for (int tau = 0; tau < NTILES; ++tau) {
        // ---- drain staged regs into swizzled LDS (+ square-sums)
#pragma unroll
        for (int k = 0; k < 8; ++k) {
            float4 v = st[k];
            sq[k] = fmaf(v.x, v.x, sq[k]);
            sq[k] = fmaf(v.y, v.y, sq[k]);
            sq[k] = fmaf(v.z, v.z, sq[k]);
            sq[k] = fmaf(v.w, v.w, sq[k]);
            tile4[lrow[k] * 32 + (lcol4 ^ (lrow[k] & 7))] = v;
        }
        __syncthreads();

        // ---- issue next tile's loads (in flight during compute below)
        if (tau + 1 < NTILES) {
            const size_t colbase = colbase0 + (size_t)(tau + 1) * TCOLS;
#pragma unroll
            for (int k = 0; k < 8; ++k)
                st[k] = *(const float4*)(qkb + (size_t)lrow[k] * NN + colbase + lcol4 * 4);
        }

        // ---- compute: wave w -> sub-slices s = 2w, 2w+1 (16 cols each)
#pragma unroll
        for (int ss = 0; ss < 2; ++ss) {
            const int s = 2 * w + ss;
            const int f0 = s * 4 + half * 2;
            const int qrow = CO + c;
            const int krow = c;
            const int sw = c & 7;
            float4 q0 = tile4[qrow * 32 + (f0 ^ sw)];
            float4 q1 = tile4[qrow * 32 + ((f0 + 1) ^ sw)];
            float4 k0 = tile4[krow * 32 + (f0 ^ sw)];
            float4 k1 = tile4[krow * 32 + ((f0 + 1) ^ sw)];

            float qf[8] = {q0.x, q0.y, q0.z, q0.w, q1.x, q1.y, q1.z, q1.w};
            float kf[8] = {k0.x, k0.y, k0.z, k0.w, k1.x, k1.y, k1.z, k1.w};

            bf16x8 ah, al, bh, bl;
#pragma unroll
            for (int j = 0; j < 8; ++j) {
                short hq = f2bf(qf[j]);
                ah[j] = hq;
                al[j] = f2bf(qf[j] - bf2f(hq));
                short hk = f2bf(kf[j]);
                bh[j] = hk;
                bl[j] = f2bf(kf[j] - bf2f(hk));
            }
            acc = __builtin_amdgcn_mfma_f32_32x32x16_bf16(ah, bh, acc, 0, 0, 0);
            acc = __builtin_amdgcn_mfma_f32_32x32x16_bf16(ah, bl, acc, 0, 0, 0);
            acc = __builtin_amdgcn_mfma_f32_32x32x16_bf16(al, bh, acc, 0, 0, 0);
        }
        __syncthreads();
    }

    // ---- stage per-wave acc: C/D layout col=lane&31 (k), row=(r&3)+8*(r>>2)+4*half (q)
#pragma unroll
    for (int r = 0; r < 16; ++r) {
        int row = (r & 3) + 8 * (r >> 2) + 4 * half;
        smem[w * 1024 + row * 32 + c] = acc[r];
    }
#pragma unroll
    for (int k = 0; k < 8; ++k)
        smem[4096 + ((t >> 5) + 8 * k) * 32 + (t & 31)] = sq[k];
    __syncthreads();

    float* pp = part + ((size_t)b * GBLK + blk) * 1024;
#pragma unroll
    for (int j = 0; j < 4; ++j) {
        int idx = t + j * 256;
        pp[idx] = smem[idx] + smem[1024 + idx] + smem[2048 + idx] + smem[3072 + idx];
    }
    if (t < 64) {
        float s = 0.f;
#pragma unroll
        for (int i = 0; i < 32; ++i) s += smem[4096 + t * 32 + i];
        partsq[((size_t)b * GBLK + blk) * 64 + t] = s;
    }
}

// ---------------------------------------------------------------------------
// Kernel B1: reduce partials over 128 chunks (unchanged from R9)
// ---------------------------------------------------------------------------
__global__ __launch_bounds__(128) void reduce_kernel(const float* __restrict__ part,
                                                     const float* __restrict__ partsq,
                                                     float* __restrict__ Sred) {
    const int b = blockIdx.y;
    const int v = blockIdx.x * 64 + (threadIdx.x >> 1);
    const int h = threadIdx.x & 1;
    float s = 0.f;
    if (v < 1024) {
        const float* p = part + (size_t)b * GBLK * 1024 + v;
        for (int ch = h * (GBLK / 2); ch < (h + 1) * (GBLK / 2); ++ch)
            s += p[(size_t)ch * 1024];
    } else {
        const float* p = partsq + (size_t)b * GBLK * 64 + (v - 1024);
        for (int ch = h * (GBLK / 2); ch < (h + 1) * (GBLK / 2); ++ch)
            s += p[(size_t)ch * 64];
    }
    s += __shfl_xor(s, 1);
    if (h == 0) Sred[b * 1088 + v] = s;
}

// ---------------------------------------------------------------------------
// Kernel B2 — EXACT R3 attn_kernel (f32 Weff)
// ---------------------------------------------------------------------------
__global__ __launch_bounds__(256) void attn_kernel(const float* __restrict__ Sred,
                                                   const float* __restrict__ w_v,
                                                   const float* __restrict__ b_v,
                                                   const float* __restrict__ temp,
                                                   float* __restrict__ Weff,
                                                   float* __restrict__ beff) {
    __shared__ float sS[1024];
    __shared__ float snorm[64];
    __shared__ float sA[1024];
    const int t = threadIdx.x;
    const int b = blockIdx.x;

    for (int i = t; i < 1024; i += 256) sS[i] = Sred[b * 1088 + i];
    if (t < 64) snorm[t] = fmaxf(sqrtf(Sred[b * 1088 + 1024 + t]), 1e-12f);
    __syncthreads();

    if (t < 32) {
        const float T = temp[0];
        const float qn = snorm[32 + t];
        float m = -1e30f;
        for (int d = 0; d < 32; ++d)
            m = fmaxf(m, sS[t * 32 + d] / (qn * snorm[d]) * T);
        float sum = 0.f;
        for (int d = 0; d < 32; ++d)
            sum += expf(sS[t * 32 + d] / (qn * snorm[d]) * T - m);
        const float inv = 1.f / sum;
        for (int d = 0; d < 32; ++d)
            sA[t * 32 + d] = expf(sS[t * 32 + d] / (qn * snorm[d]) * T - m) * inv;
    }
    __syncthreads();

    for (int idx = t; idx < CO * CIN; idx += 256) {
        int cc = idx >> 7;
        int ci = idx & 127;
        float s = 0.f;
#pragma unroll
        for (int d = 0; d < 32; ++d) s += sA[cc * 32 + d] * w_v[d * CIN + ci];
        Weff[(size_t)b * CO * CIN + idx] = s;
    }
    if (t < 32) {
        float s = 0.f;
#pragma unroll
        for (int d = 0; d < 32; ++d) s += sA[t * 32 + d] * b_v[d];
        beff[b * CO + t] = s;
    }
}

// ---------------------------------------------------------------------------
// Kernel C — out v1 with unroll 16 (single change vs R9): 16 float2 loads in
// flight per thread instead of 4. Same 2 cols/thread, scalar uniform W loads,
// ci-sequential accumulation (bit-identical result to v1).
// ---------------------------------------------------------------------------
__global__ __launch_bounds__(256) void out_kernel(const float* __restrict__ x,
                                                  const float* __restrict__ Weff,
                                                  const float* __restrict__ beff,
                                                  float* __restrict__ out) {
    const int b = blockIdx.y;
    const int n0 = blockIdx.x * 512 + threadIdx.x * 2;
    const float* xb = x + (size_t)b * CIN * NN + n0;
    const float* Wb = Weff + (size_t)b * CO * CIN;
    const float* bb = beff + b * CO;

    float a0[CO], a1[CO];
#pragma unroll
    for (int o = 0; o < CO; ++o) { a0[o] = bb[o]; a1[o] = bb[o]; }

#pragma unroll 16
    for (int ci = 0; ci < CIN; ++ci) {
        float2 xv = *(const float2*)(xb + (size_t)ci * NN);
#pragma unroll
        for (int o = 0; o < CO; ++o) {
            float wv = Wb[o * CIN + ci];
            a0[o] = fmaf(wv, xv.x, a0[o]);
            a1[o] = fmaf(wv, xv.y, a1[o]);
        }
    }

    float* ob = out + (size_t)b * CO * NN + n0;
#pragma unroll
    for (int o = 0; o < CO; ++o) {
        float2 r;
        r.x = a0[o];
        r.y = a1[o];
        *(float2*)(ob + (size_t)o * NN) = r;
    }
}

// ---------------------------------------------------------------------------
extern "C" void kernel_launch(void* const* d_in, const int* in_sizes, int n_in,
                              void* d_out, int out_size, void* d_ws, size_t ws_size,
                              hipStream_t stream) {
    const float* x    = (const float*)d_in[0];
    const float* qk   = (const float*)d_in[1];
    const float* w_v  = (const float*)d_in[2];
    const float* b_v  = (const float*)d_in[3];
    const float* temp = (const float*)d_in[4];
    float* out = (float*)d_out;

    float* part   = (float*)d_ws;                       // NB*GBLK*1024 floats (4 MB)
    float* partsq = part + (size_t)NB * GBLK * 1024;    // NB*GBLK*64 floats
    float* Sred   = partsq + (size_t)NB * GBLK * 64;    // NB*1088 floats
    float* Weff   = Sred + (size_t)NB * 1088;           // NB*CO*CIN floats
    float* beff   = Weff + (size_t)NB * CO * CIN;       // NB*CO floats

    gram_kernel<<<dim3(GBLK, NB), 256, 0, stream>>>(qk, part, partsq);
    reduce_kernel<<<dim3(17, NB), 128, 0, stream>>>(part, partsq, Sred);
    attn_kernel<<<dim3(NB), 256, 0, stream>>>(Sred, w_v, b_v, temp, Weff, beff);
    out_kernel<<<dim3(NN / 512, NB), 256, 0, stream>>>(x, Weff, beff, out);
}